// Round 7
// baseline (7367.346 us; speedup 1.0000x reference)
//
#include <hip/hip_runtime.h>

// Problem constants
#define TT   26
#define RR   100000
#define DD   128
#define NN   10
#define BB   16384
#define NUMF 13
#define KP0  3392   // T*D+NUM = 3341 padded to 53*64 (106 half-K tiles)

// mega-kernel geometry
#define NB_EMB  64            // embed driver blocks (dispatched first; never wait)
#define NB_TRP  1008          // transpose blocks (848 W0 + 128 W1 + 32 W2)
#define NB_GEMM 256           // gated L0 gemm workers (4 n-tiles x 64 m-tiles)
#define T_TAB   4096u         // units per table (16384 bags / 4 per unit)
#define T_NUM   64u           // num-fill completions (per driver block)
#define T_W0    848u          // W0 transpose tiles
#define CSTRIDE 16            // counter stride in uints (64B: avoid line contention)
#define G_BUFB  32768

typedef __bf16 bf16x8 __attribute__((ext_vector_type(8)));
typedef float  f32x4  __attribute__((ext_vector_type(4)));
typedef unsigned int u32x2 __attribute__((ext_vector_type(2)));

__device__ __forceinline__ unsigned short f2bf(float f) {
    unsigned int u = __float_as_uint(f);
    u += 0x7FFFu + ((u >> 16) & 1u);          // round-to-nearest-even
    return (unsigned short)(u >> 16);
}

__device__ __forceinline__ void gload_lds16(const void* g, void* l) {
    __builtin_amdgcn_global_load_lds(
        (const __attribute__((address_space(1))) void*)g,
        (__attribute__((address_space(3))) void*)l, 16, 0, 0);
}

// ---- producer/consumer sync helpers (agent scope, cross-XCD safe) ---------------------
__device__ __forceinline__ void wait_ge(unsigned* p, unsigned tgt) {
    if (threadIdx.x == 0) {
        while (__hip_atomic_load(p, __ATOMIC_RELAXED, __HIP_MEMORY_SCOPE_AGENT) < tgt)
            __builtin_amdgcn_s_sleep(64);
    }
    __syncthreads();
    __threadfence();   // acquire: invalidate caches so freshly-released data is visible
}

__device__ __forceinline__ void wave_release_add(unsigned* p) {
    __threadfence();   // release: drain this wave's stores to agent scope
    if ((threadIdx.x & 63) == 0)
        __hip_atomic_fetch_add(p, 1u, __ATOMIC_RELAXED, __HIP_MEMORY_SCOPE_AGENT);
}

// ======================= 256x256 4-phase counted-vmcnt MFMA GEMM core ==================
// 4 LDS buffers (4x32KB); compute h reads buf h%4 while staging h+2 -> disjoint, so
// counted vmcnt(4) at the boundary is race-free. Row-pair interleaved LDS layout:
// byte = (r>>1)*128 + (r&1)*64 + k16*16 (2-way bank alias on column reads = free).
// gate != nullptr: per-128-col table gating for the fused producer/consumer path.
__device__ __forceinline__ void gemm_core(
    const unsigned short* __restrict__ A,    // [M][K] bf16
    const unsigned short* __restrict__ Bt,   // [N][K] bf16
    const float* __restrict__ bias,
    unsigned short* __restrict__ C,          // [M][N] bf16
    int N, int K, int m0, int n0, char* lds, unsigned* gate)
{
    const int tid  = threadIdx.x;
    const int lane = tid & 63;
    const int w    = tid >> 6;
    const int wm   = w >> 2, wn = w & 3;      // 2 x 4 waves, wave-tile 128x64
    const int NT   = K >> 5;

    f32x4 acc[8][4];
    #pragma unroll
    for (int i = 0; i < 8; i++)
        #pragma unroll
        for (int j = 0; j < 4; j++) {
            f32x4 z = {0.f, 0.f, 0.f, 0.f};
            acc[i][j] = z;
        }

    auto stage_unit = [&](int h, int u) {
        int i    = ((u & 1) << 9) + tid;
        int row  = 2 * (i >> 3) + ((i >> 2) & 1);
        int col8 = i & 3;
        const unsigned short* base = (u < 2)
            ? (A  + (size_t)(m0 + row) * K)
            : (Bt + (size_t)(n0 + row) * K);
        const unsigned short* g = base + (h << 5) + col8 * 8;
        char* l = lds + (size_t)(h & 3) * G_BUFB + ((u >> 1) << 14) + ((u & 1) << 13)
                      + ((tid >> 6) << 10);
        gload_lds16(g, l);
    };

    if (gate) {                                // L0 fused path: gate w0t + table 0
        wait_ge(gate + 27 * CSTRIDE, T_W0);
        wait_ge(gate + 0, T_TAB);
    }

    #pragma unroll
    for (int u = 0; u < 4; u++) stage_unit(0, u);
    #pragma unroll
    for (int u = 0; u < 4; u++) stage_unit(1, u);
    asm volatile("s_waitcnt vmcnt(4)" ::: "memory");
    __builtin_amdgcn_s_barrier();

    for (int h = 0; h < NT; ++h) {
        const char* bufR = lds + (size_t)(h & 3) * G_BUFB;
        const bool  do_stage = (h + 2) < NT;

        if (gate && do_stage) {                // gate k-range of half-tile h+2
            int hs = h + 2;
            if ((hs & 3) == 0) {               // table boundary (104>>2 = 26 = num)
                int ts = hs >> 2;
                wait_ge(gate + ts * CSTRIDE, ts == 26 ? T_NUM : T_TAB);
            }
        }

        bf16x8 bfr[4];
        #pragma unroll
        for (int p = 0; p < 4; p++) {          // phase p computes m-frags 2p, 2p+1
            if (do_stage) stage_unit(h + 2, p);
            if (p == 0) {
                #pragma unroll
                for (int nf = 0; nf < 4; nf++) {
                    int r = wn * 64 + nf * 16 + (lane & 15);
                    bfr[nf] = *(const bf16x8*)(bufR + 16384 + ((r >> 1) << 7)
                                               + ((r & 1) << 6) + ((lane >> 4) << 4));
                }
            }
            bf16x8 afr[2];
            #pragma unroll
            for (int q = 0; q < 2; q++) {
                int r = wm * 128 + (2 * p + q) * 16 + (lane & 15);
                afr[q] = *(const bf16x8*)(bufR + ((r >> 1) << 7)
                                          + ((r & 1) << 6) + ((lane >> 4) << 4));
            }
            asm volatile("s_waitcnt lgkmcnt(0)" ::: "memory");
            __builtin_amdgcn_sched_barrier(0);
            __builtin_amdgcn_s_setprio(1);
            #pragma unroll
            for (int q = 0; q < 2; q++)
                #pragma unroll
                for (int nf = 0; nf < 4; nf++)
                    acc[2 * p + q][nf] = __builtin_amdgcn_mfma_f32_16x16x32_bf16(
                        afr[q], bfr[nf], acc[2 * p + q][nf], 0, 0, 0);
            __builtin_amdgcn_s_setprio(0);
            if (p < 3) __builtin_amdgcn_s_barrier();
        }
        if (do_stage) asm volatile("s_waitcnt vmcnt(4)" ::: "memory");
        else          asm volatile("s_waitcnt vmcnt(0)" ::: "memory");
        __builtin_amdgcn_s_barrier();
    }

    // epilogue: bias + relu + bf16 store.  C/D map: col=lane&15, row=4*(lane>>4)+j
    #pragma unroll
    for (int mf = 0; mf < 8; mf++) {
        int row_base = m0 + wm * 128 + mf * 16 + (lane >> 4) * 4;
        #pragma unroll
        for (int nf = 0; nf < 4; nf++) {
            int col = n0 + wn * 64 + nf * 16 + (lane & 15);
            float bv = bias[col];
            #pragma unroll
            for (int j = 0; j < 4; j++) {
                float v = acc[mf][nf][j] + bv;
                v = v > 0.f ? v : 0.f;
                C[(size_t)(row_base + j) * N + col] = f2bf(v);
            }
        }
    }
}

// ================= MEGA kernel: embed producers + transposes + gated L0 ================
__global__ __launch_bounds__(512, 2) void mega(
    const float* __restrict__ tables, const int* __restrict__ cat,
    const float* __restrict__ numerical, unsigned short* __restrict__ x,
    const float* __restrict__ W0, const float* __restrict__ W1,
    const float* __restrict__ W2,
    unsigned short* __restrict__ w0t, unsigned short* __restrict__ w1t,
    unsigned short* __restrict__ w2t,
    const float* __restrict__ b0, unsigned short* __restrict__ h1,
    unsigned* __restrict__ cnt)
{
    extern __shared__ __align__(16) char lds[];
    const int bid = blockIdx.x;
    const int tid = threadIdx.x;

    if (bid < NB_EMB) {
        // ------------------------- embed driver (producer) -------------------------
        const int wid8   = tid >> 6;
        const int lane   = tid & 63;
        const int wave_g = bid * 8 + wid8;         // 0..511
        // phase A: numerical + zero-pad cols [3328,3392)
        for (int row = wave_g; row < BB; row += NB_EMB * 8) {
            unsigned short v = 0;
            if (lane < NUMF) v = f2bf(numerical[row * NUMF + lane]);
            x[(size_t)row * KP0 + TT * DD + lane] = v;
        }
        __syncthreads();
        if (tid == 0) {
            __threadfence();
            __hip_atomic_fetch_add(cnt + 26 * CSTRIDE, 1u,
                                   __ATOMIC_RELAXED, __HIP_MEMORY_SCOPE_AGENT);
        }
        // phase B: bag units, t-major (one table LLC-resident), 4 bags/unit/wave
        const int half = lane >> 5;                // 0: even rows, 1: odd rows
        const int l5   = lane & 31;                // d-quad
        for (unsigned u = wave_g; u < 26u * T_TAB; u += NB_EMB * 8) {
            const int t  = u >> 12;
            const int b0i = (u & 4095) << 2;
            const float* tbase = tables + (size_t)t * RR * DD;
            f32x4 vv[4][5];
            #pragma unroll
            for (int j = 0; j < 4; j++) {
                const int* ip = cat + ((size_t)(b0i + j) * TT + t) * NN;
                #pragma unroll
                for (int n2 = 0; n2 < 5; n2++) {
                    int r = ip[2 * n2 + half];
                    vv[j][n2] = *(const f32x4*)(tbase + (size_t)r * DD + l5 * 4);
                }
            }
            #pragma unroll
            for (int j = 0; j < 4; j++) {
                f32x4 a = vv[j][0] + vv[j][1] + vv[j][2] + vv[j][3] + vv[j][4];
                float t0 = a[0] + __shfl_xor(a[0], 32, 64);
                float t1 = a[1] + __shfl_xor(a[1], 32, 64);
                float t2 = a[2] + __shfl_xor(a[2], 32, 64);
                float t3 = a[3] + __shfl_xor(a[3], 32, 64);
                if (half == 0) {
                    u32x2 pk;
                    pk[0] = (unsigned int)f2bf(t0) | ((unsigned int)f2bf(t1) << 16);
                    pk[1] = (unsigned int)f2bf(t2) | ((unsigned int)f2bf(t3) << 16);
                    *(u32x2*)(x + (size_t)(b0i + j) * KP0 + t * DD + l5 * 4) = pk;
                }
            }
            wave_release_add(cnt + t * CSTRIDE);
        }
        return;
    }

    if (bid < NB_EMB + NB_TRP) {
        // ----------------------------- transpose tiles -----------------------------
        int rel = bid - NB_EMB;
        const float* in; unsigned short* out; int Kin, KPad, N, tx, ty; bool isW0 = false;
        if (rel < 848)      { in = W0; out = w0t; Kin = TT*DD+NUMF; KPad = KP0;  N = 1024;
                              tx = rel % 53; ty = rel / 53; isW0 = true; }
        else if (rel < 976) { in = W1; out = w1t; Kin = 1024; KPad = 1024; N = 512;
                              int r2 = rel - 848; tx = r2 & 15; ty = r2 >> 4; }
        else                { in = W2; out = w2t; Kin = 512;  KPad = 512;  N = 256;
                              int r2 = rel - 976; tx = r2 & 7;  ty = r2 >> 3; }
        float (*tile)[65] = (float (*)[65])lds;
        int k0 = tx * 64, n0 = ty * 64;
        int c  = tid & 63;
        int rr = tid >> 6;                         // 0..7
        #pragma unroll
        for (int r = rr; r < 64; r += 8) {
            int k = k0 + r, n = n0 + c;
            float v = 0.f;
            if (k < Kin && n < N) v = in[(size_t)k * N + n];
            tile[r][c] = v;
        }
        __syncthreads();
        #pragma unroll
        for (int r = rr; r < 64; r += 8) {
            int n = n0 + r, kp = k0 + c;
            if (n < N && kp < KPad)
                out[(size_t)n * KPad + kp] = f2bf(tile[c][r]);
        }
        if (isW0) {
            __syncthreads();
            if (tid == 0) {
                __threadfence();
                __hip_atomic_fetch_add(cnt + 27 * CSTRIDE, 1u,
                                       __ATOMIC_RELAXED, __HIP_MEMORY_SCOPE_AGENT);
            }
        }
        return;
    }

    // -------------------------- gated L0 gemm worker (consumer) --------------------
    {
        int g   = bid - NB_EMB - NB_TRP;           // 0..255 (4 n-tiles x 64 m-tiles)
        int swz = (g & 7) * 32 + (g >> 3);         // bijective XCD swizzle (256%8==0)
        int bx  = swz & 3;
        int by  = swz >> 2;
        gemm_core(x, w0t, b0, h1, 1024, KP0, by * 256, bx * 256, lds, cnt);
    }
}

// --------------------- standalone gemm256 (L1), ungated -------------------------------
__global__ __launch_bounds__(512, 2) void gemm256(
    const unsigned short* __restrict__ A, const unsigned short* __restrict__ Bt,
    const float* __restrict__ bias, unsigned short* __restrict__ C,
    int M, int N, int K)
{
    extern __shared__ __align__(16) char lds[];
    int nwg  = gridDim.x * gridDim.y;
    int orig = blockIdx.y * gridDim.x + blockIdx.x;
    int cpx  = nwg >> 3;
    int swz  = (orig & 7) * cpx + (orig >> 3);
    int bx   = swz % gridDim.x;
    int by   = swz / gridDim.x;
    gemm_core(A, Bt, bias, C, N, K, by * 256, bx * 256, lds, nullptr);
}

// ============= fused last stage: out = relu(h2 @ W2 + b2) . W3 + b3 ====================
__global__ __launch_bounds__(256) void gemm_last(
    const unsigned short* __restrict__ A,    // h2 [BB][512] bf16
    const unsigned short* __restrict__ Bt,   // w2t [256][512] bf16
    const float* __restrict__ bias,          // b2 [256]
    const float* __restrict__ W3,            // [256]
    const float* __restrict__ b3,            // [1]
    float* __restrict__ out)                 // [BB]
{
    __shared__ __align__(16) unsigned short As[64 * 64];
    __shared__ __align__(16) unsigned short Bs[256 * 64];
    __shared__ float red[2][64];
    const int tid  = threadIdx.x;
    const int lane = tid & 63;
    const int w    = tid >> 6;
    const int wm   = w >> 1, wn = w & 1;      // wave-tile 32 rows x 128 cols
    const int m0   = blockIdx.x * 64;
    const int K = 512;

    f32x4 acc[2][8];
    #pragma unroll
    for (int i = 0; i < 2; i++)
        #pragma unroll
        for (int j = 0; j < 8; j++) {
            f32x4 z = {0.f, 0.f, 0.f, 0.f};
            acc[i][j] = z;
        }

    for (int k0 = 0; k0 < K; k0 += 64) {
        #pragma unroll
        for (int j = 0; j < 2; j++) {
            int ch = j * 256 + tid;
            const unsigned short* g = A + (size_t)(m0 + (ch >> 3)) * K + k0 + (ch & 7) * 8;
            gload_lds16(g, As + (size_t)(j * 256 + (tid & 192)) * 8);
        }
        #pragma unroll
        for (int j = 0; j < 8; j++) {
            int ch = j * 256 + tid;
            const unsigned short* g = Bt + (size_t)(ch >> 3) * K + k0 + (ch & 7) * 8;
            gload_lds16(g, Bs + (size_t)(j * 256 + (tid & 192)) * 8);
        }
        __syncthreads();
        #pragma unroll
        for (int kk = 0; kk < 2; kk++) {
            bf16x8 af[2], bfv[8];
            #pragma unroll
            for (int mi = 0; mi < 2; mi++) {
                int off = (wm * 32 + mi * 16 + (lane & 15)) * 64 + kk * 32 + (lane >> 4) * 8;
                af[mi] = *(const bf16x8*)(As + off);
            }
            #pragma unroll
            for (int ni = 0; ni < 8; ni++) {
                int off = (wn * 128 + ni * 16 + (lane & 15)) * 64 + kk * 32 + (lane >> 4) * 8;
                bfv[ni] = *(const bf16x8*)(Bs + off);
            }
            #pragma unroll
            for (int mi = 0; mi < 2; mi++)
                #pragma unroll
                for (int ni = 0; ni < 8; ni++)
                    acc[mi][ni] = __builtin_amdgcn_mfma_f32_16x16x32_bf16(
                        af[mi], bfv[ni], acc[mi][ni], 0, 0, 0);
        }
        __syncthreads();
    }

    float psum[2][4] = {{0.f,0.f,0.f,0.f},{0.f,0.f,0.f,0.f}};
    #pragma unroll
    for (int mi = 0; mi < 2; mi++)
        #pragma unroll
        for (int ni = 0; ni < 8; ni++) {
            int col = wn * 128 + ni * 16 + (lane & 15);
            float wv = W3[col], bv = bias[col];
            #pragma unroll
            for (int j = 0; j < 4; j++) {
                float v = acc[mi][ni][j] + bv;
                v = v > 0.f ? v : 0.f;
                psum[mi][j] += v * wv;
            }
        }
    #pragma unroll
    for (int off = 1; off < 16; off <<= 1)
        #pragma unroll
        for (int mi = 0; mi < 2; mi++)
            #pragma unroll
            for (int j = 0; j < 4; j++)
                psum[mi][j] += __shfl_xor(psum[mi][j], off, 64);
    if ((lane & 15) == 0) {
        #pragma unroll
        for (int mi = 0; mi < 2; mi++)
            #pragma unroll
            for (int j = 0; j < 4; j++)
                red[wn][wm * 32 + mi * 16 + (lane >> 4) * 4 + j] = psum[mi][j];
    }
    __syncthreads();
    if (tid < 64) out[m0 + tid] = red[0][tid] + red[1][tid] + b3[0];
}

extern "C" void kernel_launch(void* const* d_in, const int* in_sizes, int n_in,
                              void* d_out, int out_size, void* d_ws, size_t ws_size,
                              hipStream_t stream)
{
    const float* numerical = (const float*)d_in[0];
    const int*   cat       = (const int*)d_in[1];
    const float* tables    = (const float*)d_in[2];
    const float* W0 = (const float*)d_in[3];
    const float* b0 = (const float*)d_in[4];
    const float* W1 = (const float*)d_in[5];
    const float* b1 = (const float*)d_in[6];
    const float* W2 = (const float*)d_in[7];
    const float* b2 = (const float*)d_in[8];
    const float* W3 = (const float*)d_in[9];
    const float* b3 = (const float*)d_in[10];
    float* out = (float*)d_out;

    // workspace: [counters 4KB][x][w0t][w1t][w2t][h1]; h2 aliases x (dead after L0)
    unsigned* cnt = (unsigned*)d_ws;
    unsigned short* x   = (unsigned short*)d_ws + 2048;     // [16384][3392]
    unsigned short* w0t = x   + (size_t)BB * KP0;           // [1024][3392]
    unsigned short* w1t = w0t + (size_t)1024 * KP0;         // [512][1024]
    unsigned short* w2t = w1t + (size_t)512 * 1024;         // [256][512]
    unsigned short* h1  = w2t + (size_t)256 * 512;          // [16384][1024]
    unsigned short* h2  = x;                                // [16384][512]

    (void)hipFuncSetAttribute((const void*)mega,
                              hipFuncAttributeMaxDynamicSharedMemorySize, 131072);
    (void)hipFuncSetAttribute((const void*)gemm256,
                              hipFuncAttributeMaxDynamicSharedMemorySize, 131072);

    (void)hipMemsetAsync(cnt, 0, 4096, stream);             // zero flags every call

    mega<<<dim3(NB_EMB + NB_TRP + NB_GEMM), 512, 131072, stream>>>(
        tables, cat, numerical, x, W0, W1, W2, w0t, w1t, w2t, b0, h1, cnt);

    gemm256<<<dim3(512 / 256, BB / 256), 512, 131072, stream>>>(
        h1, w1t, b1, h2, BB, 512, 1024);
    gemm_last<<<dim3(BB / 64), 256, 0, stream>>>(h2, w2t, b2, W3, b3, out);
}

// Round 8
// 486.846 us; speedup vs baseline: 15.1328x; 15.1328x over previous
//
#include <hip/hip_runtime.h>

// Problem constants
#define TT   26
#define RR   100000
#define DD   128
#define NN   10
#define BB   16384
#define NUMF 13
#define KP0  3392   // T*D+NUM = 3341 padded to 53*64 (also /32 = 106)

typedef __bf16 bf16x8 __attribute__((ext_vector_type(8)));
typedef float  f32x4  __attribute__((ext_vector_type(4)));
typedef unsigned int u32x2 __attribute__((ext_vector_type(2)));

__device__ __forceinline__ unsigned short f2bf(float f) {
    unsigned int u = __float_as_uint(f);
    u += 0x7FFFu + ((u >> 16) & 1u);          // round-to-nearest-even
    return (unsigned short)(u >> 16);
}

__device__ __forceinline__ void gload_lds16(const void* g, void* l) {
    __builtin_amdgcn_global_load_lds(
        (const __attribute__((address_space(1))) void*)g,
        (__attribute__((address_space(3))) void*)l, 16, 0, 0);
}

// ============ fused: embedding bag (table-major) + numerical fill + weight transposes ===
// Blocks [0,1008): transpose tiles (hide under the fabric-bound embed).
// Blocks [1008, ...): one wave per bag, t-major so the active 51MB table is LLC-resident;
// two rows per gather instruction (lanes 0-31 even row, 32-63 odd, 16B/lane), one
// shfl_xor(32) combine. Trailing waves fill numerical cols [3328,3392).
#define NB_TR 1008

__global__ __launch_bounds__(256) void embed_fused(
    const float* __restrict__ tables, const int* __restrict__ cat,
    const float* __restrict__ numerical, unsigned short* __restrict__ x,
    const float* __restrict__ W0, const float* __restrict__ W1,
    const float* __restrict__ W2,
    unsigned short* __restrict__ w0t, unsigned short* __restrict__ w1t,
    unsigned short* __restrict__ w2t)
{
    __shared__ float tile[64][65];
    int bid = blockIdx.x;
    if (bid < NB_TR) {                         // ---------- transpose path ----------
        const float* in; unsigned short* out; int Kin, KPad, N, tx, ty;
        if (bid < 848)      { in = W0; out = w0t; Kin = TT*DD+NUMF; KPad = KP0;  N = 1024;
                              tx = bid % 53; ty = bid / 53; }
        else if (bid < 976) { in = W1; out = w1t; Kin = 1024; KPad = 1024; N = 512;
                              int rel = bid - 848; tx = rel & 15; ty = rel >> 4; }
        else                { in = W2; out = w2t; Kin = 512;  KPad = 512;  N = 256;
                              int rel = bid - 976; tx = rel & 7;  ty = rel >> 3; }
        int k0 = tx * 64, n0 = ty * 64;
        int c  = threadIdx.x & 63;
        int rr = threadIdx.x >> 6;
        #pragma unroll
        for (int r = rr; r < 64; r += 4) {
            int k = k0 + r, n = n0 + c;
            float v = 0.f;
            if (k < Kin && n < N) v = in[(size_t)k * N + n];
            tile[r][c] = v;
        }
        __syncthreads();
        #pragma unroll
        for (int r = rr; r < 64; r += 4) {
            int n = n0 + r, kp = k0 + c;
            if (n < N && kp < KPad)
                out[(size_t)n * KPad + kp] = f2bf(tile[c][r]);
        }
        return;
    }
    // ---------------------------------- embed path ----------------------------------
    int wid  = (bid - NB_TR) * 4 + (threadIdx.x >> 6);
    int lane = threadIdx.x & 63;
    if (wid >= BB * TT) {                      // numerical fill
        int b = wid - BB * TT;
        unsigned short v = 0;
        if (lane < NUMF) v = f2bf(numerical[b * NUMF + lane]);
        __builtin_nontemporal_store(v, x + (size_t)b * KP0 + TT * DD + lane);
        return;
    }
    int t = wid >> 14;            // wid / BB
    int b = wid & (BB - 1);       // wid % BB
    const int* ip = cat + ((size_t)b * TT + t) * NN;
    const float* tbase = tables + (size_t)t * RR * DD;
    int half = lane >> 5;
    int l5   = lane & 31;
    f32x4 acc = {0.f, 0.f, 0.f, 0.f};
    #pragma unroll
    for (int n2 = 0; n2 < 5; n2++) {
        int r = __builtin_nontemporal_load(ip + 2 * n2 + half);
        f32x4 v = *(const f32x4*)(tbase + (size_t)r * DD + l5 * 4);
        acc += v;
    }
    float t0 = acc[0] + __shfl_xor(acc[0], 32, 64);
    float t1 = acc[1] + __shfl_xor(acc[1], 32, 64);
    float t2 = acc[2] + __shfl_xor(acc[2], 32, 64);
    float t3 = acc[3] + __shfl_xor(acc[3], 32, 64);
    if (half == 0) {
        u32x2 pk;
        pk[0] = (unsigned int)f2bf(t0) | ((unsigned int)f2bf(t1) << 16);
        pk[1] = (unsigned int)f2bf(t2) | ((unsigned int)f2bf(t3) << 16);
        __builtin_nontemporal_store(pk, (u32x2*)(x + (size_t)b * KP0 + t * DD + l5 * 4));
    }
}

// ======================= 256x256 4-phase counted-vmcnt MFMA GEMM =======================
// BM=BN=256, rotation unit = half-K tile (BK=32) over 4 LDS buffers (4x32KB=128KB).
// Computing half-tile h reads buf h%4 while staging h+2 into buf (h+2)%4 -> disjoint,
// so counted vmcnt(4) at the boundary is race-free by construction.
// LDS layout per buffer: A then B, row-pair interleaved:
// byte = (r>>1)*128 + (r&1)*64 + k16*16 -> column reads 2-way bank aliased (free).
#define G_BUFB 32768

__global__ __launch_bounds__(512, 2) void gemm256(
    const unsigned short* __restrict__ A,    // [M][K] bf16
    const unsigned short* __restrict__ Bt,   // [N][K] bf16
    const float* __restrict__ bias,
    unsigned short* __restrict__ C,          // [M][N] bf16
    int M, int N, int K, int do_relu)
{
    extern __shared__ __align__(16) char lds[];
    const int tid  = threadIdx.x;
    const int lane = tid & 63;
    const int w    = tid >> 6;
    const int wm   = w >> 2, wn = w & 3;      // 2 x 4 waves, wave-tile 128x64

    // XCD-aware bijective swizzle (nwg % 8 == 0); same-by tiles stay on one XCD
    int nwg  = gridDim.x * gridDim.y;
    int orig = blockIdx.y * gridDim.x + blockIdx.x;
    int cpx  = nwg >> 3;
    int swz  = (orig & 7) * cpx + (orig >> 3);
    int bx   = swz % gridDim.x;
    int by   = swz / gridDim.x;
    const int m0 = by * 256, n0 = bx * 256;

    const int NT = K >> 5;                    // number of half-K (32) tiles

    f32x4 acc[8][4];
    #pragma unroll
    for (int i = 0; i < 8; i++)
        #pragma unroll
        for (int j = 0; j < 4; j++) {
            f32x4 z = {0.f, 0.f, 0.f, 0.f};
            acc[i][j] = z;
        }

    auto stage_unit = [&](int h, int u) {
        int i    = ((u & 1) << 9) + tid;
        int row  = 2 * (i >> 3) + ((i >> 2) & 1);
        int col8 = i & 3;
        const unsigned short* base = (u < 2)
            ? (A  + (size_t)(m0 + row) * K)
            : (Bt + (size_t)(n0 + row) * K);
        const unsigned short* g = base + (h << 5) + col8 * 8;
        char* l = lds + (size_t)(h & 3) * G_BUFB + ((u >> 1) << 14) + ((u & 1) << 13)
                      + ((tid >> 6) << 10);
        gload_lds16(g, l);
    };

    #pragma unroll
    for (int u = 0; u < 4; u++) stage_unit(0, u);
    #pragma unroll
    for (int u = 0; u < 4; u++) stage_unit(1, u);
    asm volatile("s_waitcnt vmcnt(4)" ::: "memory");
    __builtin_amdgcn_s_barrier();

    for (int h = 0; h < NT; ++h) {
        const char* bufR = lds + (size_t)(h & 3) * G_BUFB;
        const bool  do_stage = (h + 2) < NT;

        bf16x8 bfr[4];
        #pragma unroll
        for (int p = 0; p < 4; p++) {          // phase p computes m-frags 2p, 2p+1
            if (do_stage) stage_unit(h + 2, p);
            if (p == 0) {
                #pragma unroll
                for (int nf = 0; nf < 4; nf++) {
                    int r = wn * 64 + nf * 16 + (lane & 15);
                    bfr[nf] = *(const bf16x8*)(bufR + 16384 + ((r >> 1) << 7)
                                               + ((r & 1) << 6) + ((lane >> 4) << 4));
                }
            }
            bf16x8 afr[2];
            #pragma unroll
            for (int q = 0; q < 2; q++) {
                int r = wm * 128 + (2 * p + q) * 16 + (lane & 15);
                afr[q] = *(const bf16x8*)(bufR + ((r >> 1) << 7)
                                          + ((r & 1) << 6) + ((lane >> 4) << 4));
            }
            asm volatile("s_waitcnt lgkmcnt(0)" ::: "memory");
            __builtin_amdgcn_sched_barrier(0);
            __builtin_amdgcn_s_setprio(1);
            #pragma unroll
            for (int q = 0; q < 2; q++)
                #pragma unroll
                for (int nf = 0; nf < 4; nf++)
                    acc[2 * p + q][nf] = __builtin_amdgcn_mfma_f32_16x16x32_bf16(
                        afr[q], bfr[nf], acc[2 * p + q][nf], 0, 0, 0);
            __builtin_amdgcn_s_setprio(0);
            if (p < 3) __builtin_amdgcn_s_barrier();
        }
        if (do_stage) asm volatile("s_waitcnt vmcnt(4)" ::: "memory");
        else          asm volatile("s_waitcnt vmcnt(0)" ::: "memory");
        __builtin_amdgcn_s_barrier();
    }

    // epilogue: bias + relu + bf16 store.  C/D map: col=lane&15, row=4*(lane>>4)+j
    #pragma unroll
    for (int mf = 0; mf < 8; mf++) {
        int row_base = m0 + wm * 128 + mf * 16 + (lane >> 4) * 4;
        #pragma unroll
        for (int nf = 0; nf < 4; nf++) {
            int col = n0 + wn * 64 + nf * 16 + (lane & 15);
            float bv = bias[col];
            #pragma unroll
            for (int j = 0; j < 4; j++) {
                float v = acc[mf][nf][j] + bv;
                if (do_relu) v = v > 0.f ? v : 0.f;
                C[(size_t)(row_base + j) * N + col] = f2bf(v);
            }
        }
    }
}

// ============= fused last stage: out = relu(h2 @ W2 + b2) . W3 + b3 ====================
// 64-row x 256-col tiles (grid 256 = full CU coverage), 4 waves, wave-tile 32x128.
// h3 never materialized: epilogue does relu+dot in-register, shfl_xor reduce over the
// 16 col-lanes, tiny LDS cross-wave (wn) add.
__global__ __launch_bounds__(256) void gemm_last(
    const unsigned short* __restrict__ A,    // h2 [BB][512] bf16
    const unsigned short* __restrict__ Bt,   // w2t [256][512] bf16
    const float* __restrict__ bias,          // b2 [256]
    const float* __restrict__ W3,            // [256]
    const float* __restrict__ b3,            // [1]
    float* __restrict__ out)                 // [BB]
{
    __shared__ __align__(16) unsigned short As[64 * 64];
    __shared__ __align__(16) unsigned short Bs[256 * 64];
    __shared__ float red[2][64];
    const int tid  = threadIdx.x;
    const int lane = tid & 63;
    const int w    = tid >> 6;
    const int wm   = w >> 1, wn = w & 1;      // wave-tile 32 rows x 128 cols
    const int m0   = blockIdx.x * 64;
    const int K = 512;

    f32x4 acc[2][8];
    #pragma unroll
    for (int i = 0; i < 2; i++)
        #pragma unroll
        for (int j = 0; j < 8; j++) {
            f32x4 z = {0.f, 0.f, 0.f, 0.f};
            acc[i][j] = z;
        }

    for (int k0 = 0; k0 < K; k0 += 64) {
        #pragma unroll
        for (int j = 0; j < 2; j++) {          // A: 64 rows x 64k = 512 chunks
            int ch = j * 256 + tid;
            const unsigned short* g = A + (size_t)(m0 + (ch >> 3)) * K + k0 + (ch & 7) * 8;
            gload_lds16(g, As + (size_t)(j * 256 + (tid & 192)) * 8);
        }
        #pragma unroll
        for (int j = 0; j < 8; j++) {          // B: 256 rows x 64k = 2048 chunks
            int ch = j * 256 + tid;
            const unsigned short* g = Bt + (size_t)(ch >> 3) * K + k0 + (ch & 7) * 8;
            gload_lds16(g, Bs + (size_t)(j * 256 + (tid & 192)) * 8);
        }
        __syncthreads();
        #pragma unroll
        for (int kk = 0; kk < 2; kk++) {
            bf16x8 af[2], bfv[8];
            #pragma unroll
            for (int mi = 0; mi < 2; mi++) {
                int off = (wm * 32 + mi * 16 + (lane & 15)) * 64 + kk * 32 + (lane >> 4) * 8;
                af[mi] = *(const bf16x8*)(As + off);
            }
            #pragma unroll
            for (int ni = 0; ni < 8; ni++) {
                int off = (wn * 128 + ni * 16 + (lane & 15)) * 64 + kk * 32 + (lane >> 4) * 8;
                bfv[ni] = *(const bf16x8*)(Bs + off);
            }
            #pragma unroll
            for (int mi = 0; mi < 2; mi++)
                #pragma unroll
                for (int ni = 0; ni < 8; ni++)
                    acc[mi][ni] = __builtin_amdgcn_mfma_f32_16x16x32_bf16(
                        af[mi], bfv[ni], acc[mi][ni], 0, 0, 0);
        }
        __syncthreads();
    }

    // epilogue: per-thread partial dot over its 8 cols, then reduce
    float psum[2][4] = {{0.f,0.f,0.f,0.f},{0.f,0.f,0.f,0.f}};
    #pragma unroll
    for (int mi = 0; mi < 2; mi++)
        #pragma unroll
        for (int ni = 0; ni < 8; ni++) {
            int col = wn * 128 + ni * 16 + (lane & 15);
            float wv = W3[col], bv = bias[col];
            #pragma unroll
            for (int j = 0; j < 4; j++) {
                float v = acc[mi][ni][j] + bv;
                v = v > 0.f ? v : 0.f;
                psum[mi][j] += v * wv;
            }
        }
    #pragma unroll
    for (int off = 1; off < 16; off <<= 1)
        #pragma unroll
        for (int mi = 0; mi < 2; mi++)
            #pragma unroll
            for (int j = 0; j < 4; j++)
                psum[mi][j] += __shfl_xor(psum[mi][j], off, 64);
    if ((lane & 15) == 0) {
        #pragma unroll
        for (int mi = 0; mi < 2; mi++)
            #pragma unroll
            for (int j = 0; j < 4; j++)
                red[wn][wm * 32 + mi * 16 + (lane >> 4) * 4 + j] = psum[mi][j];
    }
    __syncthreads();
    if (tid < 64) out[m0 + tid] = red[0][tid] + red[1][tid] + b3[0];
}

extern "C" void kernel_launch(void* const* d_in, const int* in_sizes, int n_in,
                              void* d_out, int out_size, void* d_ws, size_t ws_size,
                              hipStream_t stream)
{
    const float* numerical = (const float*)d_in[0];
    const int*   cat       = (const int*)d_in[1];
    const float* tables    = (const float*)d_in[2];
    const float* W0 = (const float*)d_in[3];
    const float* b0 = (const float*)d_in[4];
    const float* W1 = (const float*)d_in[5];
    const float* b1 = (const float*)d_in[6];
    const float* W2 = (const float*)d_in[7];
    const float* b2 = (const float*)d_in[8];
    const float* W3 = (const float*)d_in[9];
    const float* b3 = (const float*)d_in[10];
    float* out = (float*)d_out;

    // workspace layout (bf16 elements); h2 aliases x (dead after L0)
    unsigned short* x   = (unsigned short*)d_ws;            // [16384][3392]
    unsigned short* w0t = x   + (size_t)BB * KP0;           // [1024][3392]
    unsigned short* w1t = w0t + (size_t)1024 * KP0;         // [512][1024]
    unsigned short* w2t = w1t + (size_t)512 * 1024;         // [256][512]
    unsigned short* h1  = w2t + (size_t)256 * 512;          // [16384][1024]
    unsigned short* h2  = x;                                // [16384][512]

    (void)hipFuncSetAttribute((const void*)gemm256,
                              hipFuncAttributeMaxDynamicSharedMemorySize, 131072);

    embed_fused<<<dim3(NB_TR + (BB * TT + BB) / 4), 256, 0, stream>>>(
        tables, cat, numerical, x, W0, W1, W2, w0t, w1t, w2t);

    gemm256<<<dim3(1024 / 256, BB / 256), 512, 131072, stream>>>(
        x, w0t, b0, h1, BB, 1024, KP0, 1);
    gemm256<<<dim3(512 / 256, BB / 256), 512, 131072, stream>>>(
        h1, w1t, b1, h2, BB, 512, 1024, 1);
    gemm_last<<<dim3(BB / 64), 256, 0, stream>>>(h2, w2t, b2, W3, b3, out);
}